// Round 1
// baseline (115.562 us; speedup 1.0000x reference)
//
#include <hip/hip_runtime.h>
#include <hip/hip_bf16.h>
#include <math.h>

#define NN 4096
#define DD 256
#define TWO_N 8192
#define SCALE 14.426950408889634f   // (1/T)*log2(e) = 10*1.442695...
#define INV_2N (1.0f/8192.0f)

typedef __bf16 bf16_t;
typedef bf16_t bf16x8 __attribute__((ext_vector_type(8)));
typedef bf16_t bf16x4 __attribute__((ext_vector_type(4)));
typedef float f32x4 __attribute__((ext_vector_type(4)));

// ---------------- normalize rows -> bf16 Zn ----------------
__global__ __launch_bounds__(256) void knorm(const float* __restrict__ zi,
                                             const float* __restrict__ zj,
                                             bf16_t* __restrict__ zn) {
    const int wid = threadIdx.x >> 6, lane = threadIdx.x & 63;
    const int row = blockIdx.x * 4 + wid;              // grid = 2048
    const float* src = (row < NN) ? (zi + (size_t)row * DD)
                                  : (zj + (size_t)(row - NN) * DD);
    float4 v = *(const float4*)(src + lane * 4);
    float ss = v.x*v.x + v.y*v.y + v.z*v.z + v.w*v.w;
    #pragma unroll
    for (int m = 1; m < 64; m <<= 1) ss += __shfl_xor(ss, m);
    const float sc = 1.0f / fmaxf(sqrtf(ss), 1e-8f);
    bf16x4 o;
    o[0] = (bf16_t)(v.x * sc);
    o[1] = (bf16_t)(v.y * sc);
    o[2] = (bf16_t)(v.z * sc);
    o[3] = (bf16_t)(v.w * sc);
    *(bf16x4*)(zn + (size_t)row * DD + lane * 4) = o;
}

// ---------------- main: fused sim GEMM + exp row-sum ----------------
// grid = 256 blocks (16 row-blocks x 16 col-splits), 512 threads (8 waves)
// wave = 64 rows (4 strips of 16); block = 512 rows; cols/block = 512 (32 tiles of 16)
__global__ __launch_bounds__(512, 2) void kmain(const bf16_t* __restrict__ zn,
                                                float* __restrict__ partial) {
    __shared__ char lds[2][8192];
    const int tid = threadIdx.x, wid = tid >> 6, lane = tid & 63;
    const int rb = blockIdx.x >> 4, cs = blockIdx.x & 15;
    const int rowbase = rb * 512 + wid * 64;
    const int colbase = cs * 512;
    const int ar = lane & 15, ak = lane >> 4;

    // A fragments for 64 rows x K=256, kept in registers (128 VGPRs)
    bf16x8 afrag[4][8];
    #pragma unroll
    for (int s = 0; s < 4; ++s)
        #pragma unroll
        for (int kk = 0; kk < 8; ++kk)
            afrag[s][kk] = *(const bf16x8*)(zn + (size_t)(rowbase + s*16 + ar) * DD
                                            + kk*32 + ak*8);

    float racc[4][4];
    #pragma unroll
    for (int s = 0; s < 4; ++s)
        #pragma unroll
        for (int j = 0; j < 4; ++j) racc[s][j] = 0.0f;

    const char* gz = (const char*)zn;  // rows are 512 bytes

    // stage one 16-row (8 KB) column tile into lds[buf]; linear dest,
    // inverse-XOR-swizzled global source (rule #21 both-sides pattern)
    auto stage = [&](int buf, int ct) {
        const int dd  = wid * 1024 + lane * 16;                 // linear dest in tile
        const int src = dd ^ (((dd >> 9) & 7) << 4);            // pre-swizzled source
        const char* gp = gz + (size_t)(colbase + ct * 16) * 512 + src;
        __builtin_amdgcn_global_load_lds(
            (const __attribute__((address_space(1))) void*)gp,
            (__attribute__((address_space(3))) void*)(&lds[buf][wid * 1024]),
            16, 0, 0);
    };

    stage(0, 0);

    const int brow  = lane & 15;
    const int bcol0 = (lane >> 4) * 16;
    const int bxor  = (brow & 7) << 4;
    const int baddr = brow * 512;

    for (int ct = 0; ct < 32; ++ct) {
        const int cur = ct & 1;
        __syncthreads();                       // drains vmcnt: staged tile visible
        if (ct + 1 < 32) stage(cur ^ 1, ct + 1);

        f32x4 c0 = {0,0,0,0}, c1 = {0,0,0,0}, c2 = {0,0,0,0}, c3 = {0,0,0,0};
        #pragma unroll
        for (int kk = 0; kk < 8; ++kk) {
            const int a = baddr + ((kk * 64 + bcol0) ^ bxor);   // swizzled read
            bf16x8 b = *(const bf16x8*)(&lds[cur][a]);
            c0 = __builtin_amdgcn_mfma_f32_16x16x32_bf16(afrag[0][kk], b, c0, 0, 0, 0);
            c1 = __builtin_amdgcn_mfma_f32_16x16x32_bf16(afrag[1][kk], b, c1, 0, 0, 0);
            c2 = __builtin_amdgcn_mfma_f32_16x16x32_bf16(afrag[2][kk], b, c2, 0, 0, 0);
            c3 = __builtin_amdgcn_mfma_f32_16x16x32_bf16(afrag[3][kk], b, c3, 0, 0, 0);
        }
        #pragma unroll
        for (int j = 0; j < 4; ++j) {
            racc[0][j] += __builtin_amdgcn_exp2f(c0[j] * SCALE);
            racc[1][j] += __builtin_amdgcn_exp2f(c1[j] * SCALE);
            racc[2][j] += __builtin_amdgcn_exp2f(c2[j] * SCALE);
            racc[3][j] += __builtin_amdgcn_exp2f(c3[j] * SCALE);
        }
        __syncthreads();                       // all waves done reading lds[cur]
    }

    // reduce across the 16 column-lanes, write partial row sums
    #pragma unroll
    for (int s = 0; s < 4; ++s)
        #pragma unroll
        for (int j = 0; j < 4; ++j) {
            float v = racc[s][j];
            v += __shfl_xor(v, 1); v += __shfl_xor(v, 2);
            v += __shfl_xor(v, 4); v += __shfl_xor(v, 8);
            if ((lane & 15) == 0)
                partial[cs * TWO_N + rowbase + s*16 + (lane >> 4)*4 + j] = v;
        }
}

// ---------------- final: positives + log + reduction ----------------
// grid = 64 blocks x 256 threads; wave handles 16 i's (grid-stride)
__global__ __launch_bounds__(256) void kfinal(const bf16_t* __restrict__ zn,
                                              const float* __restrict__ partial,
                                              float* __restrict__ out) {
    __shared__ float red[4];
    const int wid = threadIdx.x >> 6, lane = threadIdx.x & 63;
    const int gw = blockIdx.x * 4 + wid;       // 256 waves total
    float acc = 0.0f;
    for (int it = 0; it < 16; ++it) {
        const int i = gw + it * 256;
        const bf16_t* pa = zn + (size_t)i * DD;
        const bf16_t* pb = zn + (size_t)(i + NN) * DD;
        bf16x4 av = *(const bf16x4*)(pa + lane * 4);
        bf16x4 bv = *(const bf16x4*)(pb + lane * 4);
        float d = 0.0f;
        #pragma unroll
        for (int j = 0; j < 4; ++j) d += (float)av[j] * (float)bv[j];
        #pragma unroll
        for (int m = 1; m < 64; m <<= 1) d += __shfl_xor(d, m);
        float ri = 0.0f, rj = 0.0f;
        if (lane < 16) {
            ri = partial[lane * TWO_N + i];
            rj = partial[lane * TWO_N + i + NN];
        }
        #pragma unroll
        for (int m = 1; m < 16; m <<= 1) { ri += __shfl_xor(ri, m); rj += __shfl_xor(rj, m); }
        if (lane == 0)
            acc += logf(ri * INV_2N) + logf(rj * INV_2N) - 20.0f * d;
    }
    if (lane == 0) red[wid] = acc;
    __syncthreads();
    if (threadIdx.x == 0) {
        atomicAdd(out, (red[0] + red[1] + red[2] + red[3]) * INV_2N);
    }
}

extern "C" void kernel_launch(void* const* d_in, const int* in_sizes, int n_in,
                              void* d_out, int out_size, void* d_ws, size_t ws_size,
                              hipStream_t stream) {
    const float* zi = (const float*)d_in[0];
    const float* zj = (const float*)d_in[1];
    bf16_t* zn      = (bf16_t*)d_ws;                                  // 4 MB
    float*  partial = (float*)((char*)d_ws + (size_t)TWO_N * DD * 2); // 512 KB
    float*  out     = (float*)d_out;

    hipMemsetAsync(d_out, 0, sizeof(float), stream);
    knorm <<<TWO_N / 4, 256, 0, stream>>>(zi, zj, zn);
    kmain <<<256, 512, 0, stream>>>(zn, partial);
    kfinal<<<64, 256, 0, stream>>>(zn, partial, out);
}

// Round 2
// 103.079 us; speedup vs baseline: 1.1211x; 1.1211x over previous
//
#include <hip/hip_runtime.h>
#include <hip/hip_bf16.h>
#include <math.h>

#define NN 4096
#define DD 256
#define TWO_N 8192
#define SCALE 14.426950408889634f   // (1/T)*log2(e)
#define INV_2N (1.0f/8192.0f)

typedef __bf16 bf16_t;
typedef bf16_t bf16x8 __attribute__((ext_vector_type(8)));
typedef bf16_t bf16x4 __attribute__((ext_vector_type(4)));
typedef float f32x4 __attribute__((ext_vector_type(4)));

// ---------------- normalize rows -> bf16 Zn ; zero rowsum/possum/out ----------------
__global__ __launch_bounds__(256) void knorm(const float* __restrict__ zi,
                                             const float* __restrict__ zj,
                                             bf16_t* __restrict__ zn,
                                             float* __restrict__ rowsum,
                                             float* __restrict__ possum,
                                             float* __restrict__ out) {
    const int wid = threadIdx.x >> 6, lane = threadIdx.x & 63;
    const int b = blockIdx.x;
    if (b < 8) {                                   // zero rowsum[8192] + scalars
        f32x4 z = {0, 0, 0, 0};
        *(f32x4*)(rowsum + b * 1024 + threadIdx.x * 4) = z;
        if (b == 0 && threadIdx.x == 0) { possum[0] = 0.0f; out[0] = 0.0f; }
    }
    const int row = b * 4 + wid;                   // grid = 2048 -> rows 0..8191
    const float* src = (row < NN) ? (zi + (size_t)row * DD)
                                  : (zj + (size_t)(row - NN) * DD);
    float4 v = *(const float4*)(src + lane * 4);
    float ss = v.x*v.x + v.y*v.y + v.z*v.z + v.w*v.w;
    #pragma unroll
    for (int m = 1; m < 64; m <<= 1) ss += __shfl_xor(ss, m);
    const float sc = 1.0f / fmaxf(sqrtf(ss), 1e-8f);
    bf16x4 o;
    o[0] = (bf16_t)(v.x * sc);
    o[1] = (bf16_t)(v.y * sc);
    o[2] = (bf16_t)(v.z * sc);
    o[3] = (bf16_t)(v.w * sc);
    *(bf16x4*)(zn + (size_t)row * DD + lane * 4) = o;
}

// ---------------- main: upper-triangular 128x128 tiles of exp(sim/T) ----------------
// grid = 2080 (= 64*65/2) blocks, 256 threads (4 waves in 2x2), K=256 in 4 steps of 64.
__global__ __launch_bounds__(256, 4) void kmain(const bf16_t* __restrict__ zn,
                                                float* __restrict__ rowsum,
                                                float* __restrict__ possum) {
    __shared__ char ldsA[16384];     // [128 rows][64 bf16 = 128 B], XOR-swizzled
    __shared__ char ldsB[16384];
    const int tid = threadIdx.x, wid = tid >> 6, lane = tid & 63;

    // triangular decode (uniform scalar loop)
    int ti = 0, rem = blockIdx.x;
    while (rem >= 64 - ti) { rem -= 64 - ti; ++ti; }
    const int tj = ti + rem;
    const int rowbase = ti << 7, colbase = tj << 7;

    const int wr = wid >> 1, wc = wid & 1;         // 2x2 wave grid, 64x64 each
    const int lo = lane & 15, hi = lane >> 4;

    f32x4 acc[4][4];
    #pragma unroll
    for (int s = 0; s < 4; ++s)
        #pragma unroll
        for (int t = 0; t < 4; ++t) acc[s][t] = (f32x4){0, 0, 0, 0};

    const char* gz = (const char*)zn;              // zn rows are 512 bytes

    for (int ks = 0; ks < 4; ++ks) {
        // stage A and B 128x64 tiles: linear LDS dest (wave-uniform base),
        // inverse-XOR-swizzled per-lane global source (both-sides rule)
        #pragma unroll
        for (int p = 0; p < 4; ++p) {
            const int base = p * 4096 + wid * 1024;          // wave-uniform
            const int dd   = base + lane * 16;               // what HW writes
            const int row  = dd >> 7, col = dd & 127;
            const int scol = col ^ ((row & 7) << 4);
            const char* ga = gz + (size_t)(rowbase + row) * 512 + ks * 128 + scol;
            const char* gb = gz + (size_t)(colbase + row) * 512 + ks * 128 + scol;
            __builtin_amdgcn_global_load_lds(
                (const __attribute__((address_space(1))) void*)ga,
                (__attribute__((address_space(3))) void*)(&ldsA[base]), 16, 0, 0);
            __builtin_amdgcn_global_load_lds(
                (const __attribute__((address_space(1))) void*)gb,
                (__attribute__((address_space(3))) void*)(&ldsB[base]), 16, 0, 0);
        }
        __syncthreads();                           // drains vmcnt -> tiles visible

        #pragma unroll
        for (int kk = 0; kk < 2; ++kk) {
            bf16x8 af[4], bfr[4];
            const int kb = kk * 64 + hi * 16;
            const int sw = kb ^ ((lo & 7) << 4);   // swizzled k-offset (row&7 == lo&7)
            #pragma unroll
            for (int s = 0; s < 4; ++s) {
                af[s]  = *(const bf16x8*)(&ldsA[(wr * 64 + s * 16 + lo) * 128 + sw]);
                bfr[s] = *(const bf16x8*)(&ldsB[(wc * 64 + s * 16 + lo) * 128 + sw]);
            }
            #pragma unroll
            for (int s = 0; s < 4; ++s)
                #pragma unroll
                for (int t = 0; t < 4; ++t)
                    acc[s][t] = __builtin_amdgcn_mfma_f32_16x16x32_bf16(
                        af[s], bfr[t], acc[s][t], 0, 0, 0);
        }
        __syncthreads();                           // done reading before next stage
    }

    // ---- positives: diagonal of tiles with tj == ti+32 (col = row + 4096) ----
    if (tj == ti + 32 && wr == wc) {
        const int j = lo - hi * 4;                 // C layout: col=lo, row=hi*4+j
        float p = 0.0f;
        if (j >= 0 && j < 4) {
            #pragma unroll
            for (int s = 0; s < 4; ++s) p += acc[s][s][j];
        }
        #pragma unroll
        for (int m = 1; m < 64; m <<= 1) p += __shfl_xor(p, m);
        if (lane == 0) atomicAdd(possum, p);
    }

    // ---- exp in place ----
    #pragma unroll
    for (int s = 0; s < 4; ++s)
        #pragma unroll
        for (int t = 0; t < 4; ++t)
            #pragma unroll
            for (int j = 0; j < 4; ++j)
                acc[s][t][j] = __builtin_amdgcn_exp2f(acc[s][t][j] * SCALE);

    // ---- row sums (always) ----
    #pragma unroll
    for (int s = 0; s < 4; ++s) {
        f32x4 rs = acc[s][0] + acc[s][1] + acc[s][2] + acc[s][3];
        #pragma unroll
        for (int j = 0; j < 4; ++j) {
            float v = rs[j];
            v += __shfl_xor(v, 1); v += __shfl_xor(v, 2);
            v += __shfl_xor(v, 4); v += __shfl_xor(v, 8);
            if (lo == 0)
                atomicAdd(&rowsum[rowbase + wr * 64 + s * 16 + hi * 4 + j], v);
        }
    }

    // ---- col sums (symmetric contribution; off-diagonal tiles only) ----
    if (ti != tj) {
        #pragma unroll
        for (int t = 0; t < 4; ++t) {
            float v = 0.0f;
            #pragma unroll
            for (int s = 0; s < 4; ++s)
                v += acc[s][t][0] + acc[s][t][1] + acc[s][t][2] + acc[s][t][3];
            v += __shfl_xor(v, 16); v += __shfl_xor(v, 32);
            if (hi == 0)
                atomicAdd(&rowsum[colbase + wc * 64 + t * 16 + lo], v);
        }
    }
}

// ---------------- final: logs + scalar reduction ----------------
__global__ __launch_bounds__(256) void kfinal(const float* __restrict__ rowsum,
                                              const float* __restrict__ possum,
                                              float* __restrict__ out) {
    __shared__ float red[4];
    const int wid = threadIdx.x >> 6, lane = threadIdx.x & 63;
    const int gid = blockIdx.x * 256 + threadIdx.x;      // grid = 32 -> 8192 rows
    float v = logf(rowsum[gid] * INV_2N);
    #pragma unroll
    for (int m = 1; m < 64; m <<= 1) v += __shfl_xor(v, m);
    if (lane == 0) red[wid] = v;
    __syncthreads();
    if (threadIdx.x == 0) {
        float s = red[0] + red[1] + red[2] + red[3];
        if (blockIdx.x == 0) s -= 20.0f * possum[0];     // (1/T)*sum(pos), pos counted twice
        atomicAdd(out, s * INV_2N);
    }
}

extern "C" void kernel_launch(void* const* d_in, const int* in_sizes, int n_in,
                              void* d_out, int out_size, void* d_ws, size_t ws_size,
                              hipStream_t stream) {
    const float* zi = (const float*)d_in[0];
    const float* zj = (const float*)d_in[1];
    bf16_t* zn     = (bf16_t*)d_ws;                                   // 4 MB
    float*  rowsum = (float*)((char*)d_ws + (size_t)TWO_N * DD * 2);  // 32 KB
    float*  possum = rowsum + TWO_N;
    float*  out    = (float*)d_out;

    knorm <<<2048, 256, 0, stream>>>(zi, zj, zn, rowsum, possum, out);
    kmain <<<2080, 256, 0, stream>>>(zn, rowsum, possum);
    kfinal<<<32,   256, 0, stream>>>(rowsum, possum, out);
}